// Round 21
// baseline (994.220 us; speedup 1.0000x reference)
//
#include <hip/hip_runtime.h>
#include <math.h>

// Decoder: B=64, H=512, V=20000, Lc=128, Lce=64, Lkb=256, R=32, E=128, T=32
// Round 20 = round 19 (973us passing) + LOWP path for the mempT branch:
//  mempT is stored bf16 and consumed through tanh -> computing it with the
//  3-MFMA split path then truncating wastes 3x MFMA + split VALU.  New LOWP
//  template flag: round inputs to bf16, ONE MFMA per fragment pair.
//  Applied ONLY to mempT (Gx/proj keep split precision: recurrent h-path and
//  softmax logits compound errors).
// Everything else identical to round 19.  LDS-staged gemm_split BANNED.
// No atomics -> deterministic.

#define BN   64
#define HN   512
#define VN   20000
#define LCN  128
#define LCEN 64
#define LKBN 256
#define RN   32
#define EN   128
#define TN   32
#define NEGV -1e9f

typedef __attribute__((ext_vector_type(8))) short bf16x8;
typedef __attribute__((ext_vector_type(4))) float f32x4;

__device__ __forceinline__ float fast_tanh(float x) {
  float e = __expf(2.f * x);
  return 1.f - __fdividef(2.f, 1.f + e);
}
__device__ __forceinline__ float fast_sigm(float x) {
  return __fdividef(1.f, 1.f + __expf(-x));
}

__device__ __forceinline__ unsigned short f2bf(float f) {
  unsigned int u = __float_as_uint(f);
  unsigned int r = (u + 0x7FFFu + ((u >> 16) & 1u)) >> 16;
  return (unsigned short)r;
}
__device__ __forceinline__ float bf2f(unsigned short u) {
  return __uint_as_float((unsigned int)u << 16);
}

// Truncation split: hi = top 16 bits (v - hi exact), lo = round(v - hi).
__device__ __forceinline__ void split8(const float* v, bf16x8& hi, bf16x8& lo) {
#pragma unroll
  for (int i = 0; i < 8; ++i) {
    unsigned int u = __float_as_uint(v[i]);
    unsigned short h = (unsigned short)(u >> 16);
    hi[i] = (short)h;
    lo[i] = (short)f2bf(v[i] - __uint_as_float((unsigned int)h << 16));
  }
}

// Round-to-nearest bf16 (LOWP path).
__device__ __forceinline__ void round8(const float* v, bf16x8& hi) {
#pragma unroll
  for (int i = 0; i < 8; ++i) hi[i] = (short)f2bf(v[i]);
}

// ---------------------------------------------------------------------------
// LDS-free MFMA GEMM body (proven pattern, rounds 5-19).
// EPI: 0 plain f32 (+bias); 1 relu f32 (+bias); 2 cat bf16(tanh(x+addm+bias));
//      3 TRS f32 store; 4 TRS bf16 store.
// LOWP: inputs rounded to bf16, single MFMA (for bf16-stored tanh-consumed
//       outputs only).
// ---------------------------------------------------------------------------
template <int EPI, bool GATHER, bool PROJ, bool LOWP = false>
__device__ __forceinline__ void gemm_mfma_body(
    int bx, int by,
    const float* __restrict__ A, const float* __restrict__ W, int wstride,
    const float* __restrict__ bias, const int* __restrict__ target,
    const float* __restrict__ addm, int astride,
    const float* __restrict__ Wce, const float* __restrict__ Wkb,
    const float* __restrict__ Wq, const float* __restrict__ Wc,
    float* __restrict__ Cf, unsigned short* __restrict__ Cb,
    int M, int N, int K)
{
  int tid = threadIdx.x & 255, wv = tid >> 6, lane = tid & 63;
  int m0 = bx * 64, n0 = by * 64;
  int wm = (wv >> 1) * 32, wn = (wv & 1) * 32;
  int lr = lane & 15, kg = (lane >> 4) * 8;

  const float* arow[2];
#pragma unroll
  for (int mt = 0; mt < 2; ++mt) {
    int m = m0 + wm + mt * 16 + lr;
    if (GATHER) {
      int tt = m >> 6, bb = m & 63;
      int tok = (tt == 0) ? 2 : target[bb * TN + (tt - 1)];
      arow[mt] = A + (size_t)tok * K + kg;
    } else {
      arow[mt] = A + (size_t)m * K + kg;
    }
  }
  const float* wrow[2];
#pragma unroll
  for (int nt = 0; nt < 2; ++nt) {
    int nr = n0 + wn + nt * 16 + lr;
    if (PROJ) {
      if (nr < 512)       wrow[nt] = Wce + (size_t)nr * 512 + kg;
      else if (nr < 1024) wrow[nt] = Wkb + (size_t)(nr - 512) * 512 + kg;
      else if (nr < 1536) wrow[nt] = Wq + (size_t)(nr - 1024) * 512 + kg;
      else                wrow[nt] = Wc + (size_t)(nr - 1536) * 1536 + kg;
    } else {
      wrow[nt] = W + (size_t)nr * wstride + kg;
    }
  }

  f32x4 acc[2][2];
#pragma unroll
  for (int i = 0; i < 2; ++i)
#pragma unroll
    for (int j = 0; j < 2; ++j) acc[i][j] = (f32x4){0.f, 0.f, 0.f, 0.f};

  for (int ko = 0; ko < K; ko += 32) {
    bf16x8 ah[2], al[2], bh[2], bl[2];
#pragma unroll
    for (int mt = 0; mt < 2; ++mt) {
      float av[8];
      *(float4*)(av + 0) = *(const float4*)(arow[mt] + ko);
      *(float4*)(av + 4) = *(const float4*)(arow[mt] + ko + 4);
      if (LOWP) round8(av, ah[mt]);
      else split8(av, ah[mt], al[mt]);
    }
#pragma unroll
    for (int nt = 0; nt < 2; ++nt) {
      float wv8[8];
      *(float4*)(wv8 + 0) = *(const float4*)(wrow[nt] + ko);
      *(float4*)(wv8 + 4) = *(const float4*)(wrow[nt] + ko + 4);
      if (LOWP) round8(wv8, bh[nt]);
      else split8(wv8, bh[nt], bl[nt]);
    }
#pragma unroll
    for (int mt = 0; mt < 2; ++mt)
#pragma unroll
      for (int nt = 0; nt < 2; ++nt) {
        acc[mt][nt] = __builtin_amdgcn_mfma_f32_16x16x32_bf16(ah[mt], bh[nt], acc[mt][nt], 0, 0, 0);
        if (!LOWP) {
          acc[mt][nt] = __builtin_amdgcn_mfma_f32_16x16x32_bf16(ah[mt], bl[nt], acc[mt][nt], 0, 0, 0);
          acc[mt][nt] = __builtin_amdgcn_mfma_f32_16x16x32_bf16(al[mt], bh[nt], acc[mt][nt], 0, 0, 0);
        }
      }
  }

#pragma unroll
  for (int mt = 0; mt < 2; ++mt)
#pragma unroll
    for (int nt = 0; nt < 2; ++nt) {
      int col = n0 + wn + nt * 16 + lr;
      int rowb = m0 + wm + mt * 16 + (lane >> 4) * 4;
#pragma unroll
      for (int r = 0; r < 4; ++r) {
        int m = rowb + r;
        float v = acc[mt][nt][r];
        if (EPI == 0) {
          if (bias) v += bias[col];
          Cf[(size_t)m * N + col] = v;
        } else if (EPI == 1) {
          if (bias) v += bias[col];
          Cf[(size_t)m * N + col] = fmaxf(v, 0.f);
        } else if (EPI == 2) {
          v += addm[(size_t)m * astride + col] + bias[col];
          Cb[(size_t)m * N + col] = f2bf(fast_tanh(v));
        } else if (EPI == 3) {
          Cf[((size_t)(m >> 7) * N + col) * 128 + (m & 127)] = v;
        } else {
          Cb[((size_t)(m >> 7) * N + col) * 128 + (m & 127)] = f2bf(v);
        }
      }
    }
}

template <int EPI, bool GATHER, bool PROJ>
__global__ __launch_bounds__(256) void gemm_mfma(
    const float* __restrict__ A, const float* __restrict__ W, int wstride,
    const float* __restrict__ bias, const int* __restrict__ target,
    const float* __restrict__ addm, int astride,
    const float* __restrict__ Wce, const float* __restrict__ Wkb,
    const float* __restrict__ Wq, const float* __restrict__ Wc,
    float* __restrict__ Cf, unsigned short* __restrict__ Cb,
    int M, int N, int K)
{
  gemm_mfma_body<EPI, GATHER, PROJ>(blockIdx.x, blockIdx.y, A, W, wstride,
                                    bias, target, addm, astride, Wce, Wkb, Wq,
                                    Wc, Cf, Cb, M, N, K);
}

// ---------------------------------------------------------------------------
// setup_a: ALL independent setup in one dispatch.  grid 7632, 256 thr.
//   [0,768) Whh split | [768,776) h0 | [776,1544) Gx | [1544,1608) CSR |
//   [1608,6608) Wv conv | [6608,7632) mempT (LOWP bf16 GEMM, EPI=4)
// ---------------------------------------------------------------------------
__global__ __launch_bounds__(256) void setup_a(
    const float* __restrict__ Whh, unsigned short* __restrict__ WhhH,
    unsigned short* __restrict__ WhhL,
    const float* __restrict__ ch, const float* __restrict__ Wp,
    const float* __restrict__ bp, float* __restrict__ hall,
    const float* __restrict__ emb, const int* __restrict__ target,
    const float* __restrict__ Wih, const float* __restrict__ bih,
    float* __restrict__ Gx,
    const int* __restrict__ kbid, const int* __restrict__ ceid,
    const int* __restrict__ krow,
    int* __restrict__ kbo, int* __restrict__ kbi,
    int* __restrict__ ceo, int* __restrict__ cei,
    int* __restrict__ rwo, int* __restrict__ rwi,
    const float* __restrict__ Wv, unsigned short* __restrict__ Wvb,
    const float* __restrict__ ctx, const float* __restrict__ Wm,
    unsigned short* __restrict__ mempTb)
{
  int bid = blockIdx.x, tid = threadIdx.x;
  if (bid < 768) {
    int i = (bid * 256 + tid) * 4;
    if (i >= 1536 * 512) return;
    float4 v = *(const float4*)(Whh + i);
    float vv[4] = {v.x, v.y, v.z, v.w};
#pragma unroll
    for (int j = 0; j < 4; ++j) {
      unsigned int u = __float_as_uint(vv[j]);
      unsigned short h = (unsigned short)(u >> 16);
      WhhH[i + j] = h;
      WhhL[i + j] = f2bf(vv[j] - __uint_as_float((unsigned int)h << 16));
    }
  } else if (bid < 776) {
    gemm_mfma_body<1, false, false>(0, bid - 768, ch, Wp, 512, bp, nullptr,
                                    nullptr, 0, nullptr, nullptr, nullptr,
                                    nullptr, hall, nullptr, 64, 512, 512);
  } else if (bid < 1544) {
    int i = bid - 776;
    gemm_mfma_body<0, true, false>(i % 32, i / 32, emb, Wih, 512, bih, target,
                                   nullptr, 0, nullptr, nullptr, nullptr,
                                   nullptr, Gx, nullptr, 2048, 1536, 512);
  } else if (bid < 1608) {
    int b = bid - 1544;
    __shared__ int sid[256], srw[256], scid[64];
    __shared__ int cnt[128], off[129];
    sid[tid] = kbid[b * LKBN + tid];
    srw[tid] = krow[b * LKBN + tid];
    if (tid < 64) scid[tid] = ceid[b * LCEN + tid];
    __syncthreads();
    if (tid < 128) {
      int c = 0;
      for (int k = 0; k < 256; ++k) c += (sid[k] == tid);
      cnt[tid] = c;
    }
    __syncthreads();
    if (tid == 0) {
      int o = 0;
      for (int e = 0; e < 128; ++e) { off[e] = o; o += cnt[e]; }
      off[128] = o;
    }
    __syncthreads();
    if (tid < 128) {
      int w = off[tid];
      for (int k = 0; k < 256; ++k) if (sid[k] == tid) kbi[b * 256 + (w++)] = k;
      kbo[b * 129 + tid] = off[tid];
      if (tid == 0) kbo[b * 129 + 128] = off[128];
    }
    __syncthreads();
    if (tid < 128) {
      int c = 0;
      for (int k = 0; k < 64; ++k) c += (scid[k] == tid);
      cnt[tid] = c;
    }
    __syncthreads();
    if (tid == 0) {
      int o = 0;
      for (int e = 0; e < 128; ++e) { off[e] = o; o += cnt[e]; }
      off[128] = o;
    }
    __syncthreads();
    if (tid < 128) {
      int w = off[tid];
      for (int k = 0; k < 64; ++k) if (scid[k] == tid) cei[b * 64 + (w++)] = k;
      ceo[b * 129 + tid] = off[tid];
      if (tid == 0) ceo[b * 129 + 128] = off[128];
    }
    __syncthreads();
    if (tid < 32) {
      int c = 0;
      for (int k = 0; k < 256; ++k) c += (srw[k] == tid);
      cnt[tid] = c;
    }
    __syncthreads();
    if (tid == 0) {
      int o = 0;
      for (int r = 0; r < 32; ++r) { off[r] = o; o += cnt[r]; }
      off[32] = o;
    }
    __syncthreads();
    if (tid < 32) {
      int w = off[tid];
      for (int k = 0; k < 256; ++k) if (srw[k] == tid) rwi[b * 256 + (w++)] = k;
      rwo[b * 33 + tid] = off[tid];
      if (tid == 0) rwo[b * 33 + 32] = off[32];
    }
  } else if (bid < 6608) {
    size_t i = ((size_t)(bid - 1608) * 256 + tid) * 8;
    if (i >= (size_t)VN * HN) return;
    float4 v0 = *(const float4*)(Wv + i);
    float4 v1 = *(const float4*)(Wv + i + 4);
    unsigned short o[8];
    o[0] = f2bf(v0.x); o[1] = f2bf(v0.y); o[2] = f2bf(v0.z); o[3] = f2bf(v0.w);
    o[4] = f2bf(v1.x); o[5] = f2bf(v1.y); o[6] = f2bf(v1.z); o[7] = f2bf(v1.w);
    *(uint4*)(Wvb + i) = *(const uint4*)o;
  } else {
    int i = bid - 6608;
    gemm_mfma_body<4, false, false, true>(i % 128, i / 128, ctx, Wm, 512,
                                          nullptr, nullptr, nullptr, 0,
                                          nullptr, nullptr, nullptr, nullptr,
                                          nullptr, mempTb, 8192, 512, 512);
  }
}

// ---------------------------------------------------------------------------
// row_agg: thread-per-output via CSR (round-19 proven).  grid 4096, 256 thr.
// ---------------------------------------------------------------------------
__global__ __launch_bounds__(256) void row_agg(
    const float* __restrict__ kb, float* __restrict__ rowh,
    const int* __restrict__ rwo, const int* __restrict__ rwi)
{
  int s = blockIdx.x, tid = threadIdx.x;
  int b = s >> 6;
  int rem = s & 63;
  int r = rem >> 1, half = rem & 1;
  int h = half * 256 + tid;
  int p0 = rwo[b * 33 + r], p1 = rwo[b * 33 + r + 1];
  const float* kbb = kb + (size_t)b * LKBN * HN + h;
  float sum = 0.f;
  for (int p = p0; p < p1; ++p)
    sum += kbb[(size_t)rwi[b * 256 + p] * HN];
  float cnt = (float)(p1 - p0);
  rowh[((size_t)b * RN + r) * HN + h] = sum / fmaxf(cnt, 1.f);
}

// ---------------------------------------------------------------------------
// Serial GRU step, 512 thr / 8 waves, 2-way K-split (round-10 proven).
// ---------------------------------------------------------------------------
__global__ __launch_bounds__(512) void step_gru(
    const float* __restrict__ Gx, const float* __restrict__ hprev,
    float* __restrict__ hnew, const unsigned short* __restrict__ WhhH,
    const unsigned short* __restrict__ WhhL, const float* __restrict__ bhh)
{
  __shared__ float red[3072];
  int tid = threadIdx.x;
  int w = tid >> 6, lane = tid & 63;
  int kh = w >> 2, mg = w & 3;
  int j0 = blockIdx.x * 16;
  int m0 = mg * 16;
  int lr = lane & 15, kg = (lane >> 4) * 8;
  int kbase = kh * 256;

  f32x4 acc[3];
#pragma unroll
  for (int g = 0; g < 3; ++g) acc[g] = (f32x4){0.f, 0.f, 0.f, 0.f};
  const float* ap = hprev + (size_t)(m0 + lr) * 512 + kbase + kg;
  const unsigned short* bhp = WhhH + (size_t)(j0 + lr) * 512 + kbase + kg;
  const unsigned short* blp = WhhL + (size_t)(j0 + lr) * 512 + kbase + kg;
#pragma unroll
  for (int ks = 0; ks < 8; ++ks) {
    int ko = ks * 32;
    float av[8];
    *(float4*)(av + 0) = *(const float4*)(ap + ko);
    *(float4*)(av + 4) = *(const float4*)(ap + ko + 4);
    bf16x8 ah, al;
    split8(av, ah, al);
#pragma unroll
    for (int g = 0; g < 3; ++g) {
      bf16x8 bh = *(const bf16x8*)(bhp + (size_t)g * 512 * 512 + ko);
      bf16x8 bl = *(const bf16x8*)(blp + (size_t)g * 512 * 512 + ko);
      acc[g] = __builtin_amdgcn_mfma_f32_16x16x32_bf16(ah, bh, acc[g], 0, 0, 0);
      acc[g] = __builtin_amdgcn_mfma_f32_16x16x32_bf16(ah, bl, acc[g], 0, 0, 0);
      acc[g] = __builtin_amdgcn_mfma_f32_16x16x32_bf16(al, bh, acc[g], 0, 0, 0);
    }
  }

  if (kh == 1) {
#pragma unroll
    for (int g = 0; g < 3; ++g)
#pragma unroll
      for (int r = 0; r < 4; ++r)
        red[(mg * 3 + g) * 256 + lane * 4 + r] = acc[g][r];
  }
  __syncthreads();
  if (kh == 0) {
#pragma unroll
    for (int g = 0; g < 3; ++g)
#pragma unroll
      for (int r = 0; r < 4; ++r)
        acc[g][r] += red[(mg * 3 + g) * 256 + lane * 4 + r];
    int j = j0 + lr;
#pragma unroll
    for (int r = 0; r < 4; ++r) {
      int b = m0 + (lane >> 4) * 4 + r;
      const float* gx = Gx + (size_t)b * 1536;
      float rr = fast_sigm(gx[j] + acc[0][r] + bhh[j]);
      float z  = fast_sigm(gx[512 + j] + acc[1][r] + bhh[512 + j]);
      float n  = fast_tanh(gx[1024 + j] + rr * (acc[2][r] + bhh[1024 + j]));
      float hp = hprev[(size_t)b * 512 + j];
      hnew[(size_t)b * 512 + j] = (1.f - z) * n + z * hp;
    }
  }
}

// ---------------------------------------------------------------------------
// Fused attention logits.  grid (64, 27), 256 thr.  mempT read as bf16.
// ---------------------------------------------------------------------------
__global__ __launch_bounds__(256) void attn_logits(
    const float* __restrict__ qp, const float* __restrict__ kb,
    const float* __restrict__ ce, const float* __restrict__ rowh,
    const unsigned short* __restrict__ mempTb, const float* __restrict__ va,
    const float* __restrict__ ba, float* __restrict__ logits,
    float* __restrict__ pmlp)
{
  int b = blockIdx.x, nt = blockIdx.y;
  int tid = threadIdx.x;
  if (nt < 11) {
    int wv = tid >> 6, lane = tid & 63;
    int lr = lane & 15, kg = (lane >> 4) * 8;
    const float* keys; int keybase, qoff, gkbase;
    if (nt < 8)       { keys = kb + (size_t)b * 256 * 512;  keybase = nt * 32;       qoff = 512; gkbase = keybase; }
    else if (nt < 10) { keys = ce + (size_t)b * 64 * 512;   keybase = (nt - 8) * 32; qoff = 0;   gkbase = 256 + keybase; }
    else              { keys = rowh + (size_t)b * 32 * 512; keybase = 0;             qoff = 512; gkbase = 320; }
    int mhalf = wv >> 1, nhalf = wv & 1;
    const float* ap = qp + (size_t)((mhalf * 16 + lr) * 64 + b) * 2048 + qoff + kg;
    const float* bp = keys + (size_t)(keybase + nhalf * 16 + lr) * 512 + kg;
    f32x4 acc = {0.f, 0.f, 0.f, 0.f};
#pragma unroll 4
    for (int ks = 0; ks < 16; ++ks) {
      int ko = ks * 32;
      float av[8], bv[8];
      *(float4*)(av + 0) = *(const float4*)(ap + ko);
      *(float4*)(av + 4) = *(const float4*)(ap + ko + 4);
      *(float4*)(bv + 0) = *(const float4*)(bp + ko);
      *(float4*)(bv + 4) = *(const float4*)(bp + ko + 4);
      bf16x8 ah, al, bh, bl;
      split8(av, ah, al);
      split8(bv, bh, bl);
      acc = __builtin_amdgcn_mfma_f32_16x16x32_bf16(ah, bh, acc, 0, 0, 0);
      acc = __builtin_amdgcn_mfma_f32_16x16x32_bf16(ah, bl, acc, 0, 0, 0);
      acc = __builtin_amdgcn_mfma_f32_16x16x32_bf16(al, bh, acc, 0, 0, 0);
    }
    int gk = gkbase + nhalf * 16 + lr;
#pragma unroll
    for (int r = 0; r < 4; ++r) {
      int t = mhalf * 16 + (lane >> 4) * 4 + r;
      logits[((size_t)b * 32 + t) * 352 + gk] = acc[r];
    }
  } else {
    int zz = nt - 11;
    int ch = zz & 3, tg = zz >> 2;
    int h0 = ch << 7;
    __shared__ float sq[8][128];
    __shared__ float sv[128];
    for (int idx = tid; idx < 1024; idx += 256) {
      int tl = idx >> 7, i = idx & 127;
      int t = tg * 8 + tl;
      sq[tl][i] = qp[(size_t)(t * 64 + b) * 2048 + 1024 + h0 + i] + ba[h0 + i];
    }
    if (tid < 128) sv[tid] = va[h0 + tid];
    __syncthreads();
    int k = tid & 127, th = tid >> 7;
    const unsigned short* mp = mempTb + ((size_t)b * 512 + h0) * 128 + k;
    float acc[4] = {};
    for (int h = 0; h < 128; ++h) {
      float mv = bf2f(mp[h * 128]);
      float vah = sv[h];
#pragma unroll
      for (int i = 0; i < 4; ++i)
        acc[i] += vah * fast_tanh(sq[th * 4 + i][h] + mv);
    }
#pragma unroll
    for (int i = 0; i < 4; ++i) {
      int t = tg * 8 + th * 4 + i;
      pmlp[(((size_t)b * 4 + ch) * 32 + t) * 128 + k] = acc[i];
    }
  }
}

// ---------------------------------------------------------------------------
// Reduce: softmaxes + p_entity + weights out (CSR-bucketed, __expf).
// grid (64, 32), 256 thr.
// ---------------------------------------------------------------------------
__global__ __launch_bounds__(256) void attn_reduce_all(
    const float* __restrict__ logits, const float* __restrict__ pmlp,
    const float* __restrict__ hall, const float* __restrict__ Wsw,
    const float* __restrict__ bsw, const int* __restrict__ krow,
    const int* __restrict__ kbo, const int* __restrict__ kbi,
    const int* __restrict__ ceo, const int* __restrict__ cei,
    const int* __restrict__ rwo, const int* __restrict__ rwi,
    float* __restrict__ pout, float* __restrict__ wall,
    float* __restrict__ pswall)
{
  int b = blockIdx.x, t = blockIdx.y, tid = threadIdx.x;
  int wv = tid >> 6, lane = tid & 63;
  __shared__ float s_l[480];
  __shared__ float s_kbp[256];
  __shared__ float s_wce[64], s_wrow[32], s_wc[128];
  __shared__ float s_rmax[32], s_rsum[32];
  __shared__ int s_krow[256];
  __shared__ float s_red[4];
  __shared__ float s_psw;

  const float* lg = logits + ((size_t)b * 32 + t) * 352;
  for (int k = tid; k < 352; k += 256) s_l[k] = lg[k];
  if (tid < 128) {
    const float* pm = pmlp + ((size_t)b * 4 * 32 + t) * 128 + tid;
    s_l[352 + tid] = pm[0] + pm[4096] + pm[8192] + pm[12288];
  }
  {
    const float* hp = hall + ((size_t)(t + 1) * 64 + b) * 512;
    float ps = hp[tid] * Wsw[tid] + hp[tid + 256] * Wsw[tid + 256];
    for (int o = 32; o; o >>= 1) ps += __shfl_down(ps, o);
    if (lane == 0) s_red[wv] = ps;
  }
  s_krow[tid] = krow[b * LKBN + tid];
  __syncthreads();
  if (tid == 0) s_psw = fast_sigm(s_red[0] + s_red[1] + s_red[2] + s_red[3] + bsw[0]);

  if (wv == 0) {
    {
      float v = s_l[256 + lane];
      float m = v;
      for (int o = 32; o; o >>= 1) m = fmaxf(m, __shfl_xor(m, o));
      float e = __expf(v - m), s = e;
      for (int o = 32; o; o >>= 1) s += __shfl_xor(s, o);
      s_wce[lane] = e / s;
    }
    {
      float v;
      if (lane < 32) {
        bool empty = rwo[b * 33 + lane + 1] == rwo[b * 33 + lane];
        v = empty ? NEGV : s_l[320 + lane];
      } else v = -INFINITY;
      float m = v;
      for (int o = 32; o; o >>= 1) m = fmaxf(m, __shfl_xor(m, o));
      float e = (lane < 32) ? __expf(v - m) : 0.f, s = e;
      for (int o = 32; o; o >>= 1) s += __shfl_xor(s, o);
      if (lane < 32) s_wrow[lane] = e / s;
    }
  } else if (wv == 1) {
    float v0 = s_l[352 + lane], v1 = s_l[352 + 64 + lane];
    float m = fmaxf(v0, v1);
    for (int o = 32; o; o >>= 1) m = fmaxf(m, __shfl_xor(m, o));
    float e0 = __expf(v0 - m), e1 = __expf(v1 - m);
    float s = e0 + e1;
    for (int o = 32; o; o >>= 1) s += __shfl_xor(s, o);
    s_wc[lane] = e0 / s;
    s_wc[lane + 64] = e1 / s;
  } else {
    int r = (tid - 128) >> 2, i = (tid - 128) & 3;
    int p0 = rwo[b * 33 + r], p1 = rwo[b * 33 + r + 1];
    float m = -INFINITY;
    for (int p = p0 + i; p < p1; p += 4) m = fmaxf(m, s_l[rwi[b * 256 + p]]);
    for (int o = 2; o; o >>= 1) m = fmaxf(m, __shfl_xor(m, o));
    float s = 0.f;
    for (int p = p0 + i; p < p1; p += 4) s += __expf(s_l[rwi[b * 256 + p]] - m);
    for (int o = 2; o; o >>= 1) s += __shfl_xor(s, o);
    if (i == 0) { s_rmax[r] = m; s_rsum[r] = s; }
  }
  __syncthreads();
  {
    int r = s_krow[tid];
    s_kbp[tid] = __expf(s_l[tid] - s_rmax[r]) / s_rsum[r] * s_wrow[r];
  }
  __syncthreads();
  if (tid < EN) {
    float a = 0.f;
    for (int p = ceo[b * 129 + tid]; p < ceo[b * 129 + tid + 1]; ++p)
      a += s_wce[cei[b * 64 + p]];
    float pk = 0.f;
    for (int p = kbo[b * 129 + tid]; p < kbo[b * 129 + tid + 1]; ++p)
      pk += s_kbp[kbi[b * 256 + p]];
    float psw = s_psw;
    pout[((size_t)t * BN + b) * EN + tid] = (1.f - psw) * a + psw * pk;
  }
  float* wb = wall + (size_t)(b * 32 + t) * 224;
  if (tid < 64) wb[tid] = s_wce[tid];
  else if (tid < 96) wb[tid] = s_wrow[tid - 64];
  else if (tid < 224) wb[tid] = s_wc[tid - 96];
  if (tid == 0) pswall[b * 32 + t] = s_psw;
}

// ---------------------------------------------------------------------------
// Batched weighted sums.  grid (64, 2, 2), 256 thr.  kind z: 0=ctx, 1=entity.
// ---------------------------------------------------------------------------
__global__ __launch_bounds__(256) void attn_wsum_all(
    const float* __restrict__ wall, const float* __restrict__ pswall,
    const float* __restrict__ ctx, const float* __restrict__ ce,
    const float* __restrict__ rowh, float* __restrict__ cinall)
{
  int b = blockIdx.x, half = blockIdx.y, kind = blockIdx.z;
  int tid = threadIdx.x;
  int h = half * 256 + tid;
  if (kind == 0) {
    __shared__ float wc[32][128];
    for (int idx = tid; idx < 4096; idx += 256)
      wc[idx >> 7][idx & 127] = wall[(size_t)(b * 32 + (idx >> 7)) * 224 + 96 + (idx & 127)];
    __syncthreads();
    const float* xb = ctx + (size_t)b * 128 * 512 + h;
    float acc[32] = {};
    for (int k = 0; k < 128; k += 4) {
      float v0 = xb[(k + 0) * 512], v1 = xb[(k + 1) * 512];
      float v2 = xb[(k + 2) * 512], v3 = xb[(k + 3) * 512];
#pragma unroll
      for (int t = 0; t < 32; ++t) {
        float4 w = *(const float4*)&wc[t][k];
        acc[t] += w.x * v0 + w.y * v1 + w.z * v2 + w.w * v3;
      }
    }
    for (int t = 0; t < 32; ++t)
      cinall[(size_t)(t * 64 + b) * 1024 + h] = acc[t];
  } else {
    __shared__ float wce[32][64];
    __shared__ float wr[32][32];
    __shared__ float sps[32];
    for (int idx = tid; idx < 2048; idx += 256)
      wce[idx >> 6][idx & 63] = wall[(size_t)(b * 32 + (idx >> 6)) * 224 + (idx & 63)];
    for (int idx = tid; idx < 1024; idx += 256)
      wr[idx >> 5][idx & 31] = wall[(size_t)(b * 32 + (idx >> 5)) * 224 + 64 + (idx & 31)];
    if (tid < 32) sps[tid] = pswall[b * 32 + tid];
    __syncthreads();
    const float* cb = ce + (size_t)b * 64 * 512 + h;
    float ac[32] = {};
    for (int k = 0; k < 64; k += 4) {
      float v0 = cb[(k + 0) * 512], v1 = cb[(k + 1) * 512];
      float v2 = cb[(k + 2) * 512], v3 = cb[(k + 3) * 512];
#pragma unroll
      for (int t = 0; t < 32; ++t) {
        float4 w = *(const float4*)&wce[t][k];
        ac[t] += w.x * v0 + w.y * v1 + w.z * v2 + w.w * v3;
      }
    }
    const float* rb = rowh + (size_t)b * 32 * 512 + h;
    float ar[32] = {};
    for (int k = 0; k < 32; k += 4) {
      float v0 = rb[(k + 0) * 512], v1 = rb[(k + 1) * 512];
      float v2 = rb[(k + 2) * 512], v3 = rb[(k + 3) * 512];
#pragma unroll
      for (int t = 0; t < 32; ++t) {
        float4 w = *(const float4*)&wr[t][k];
        ar[t] += w.x * v0 + w.y * v1 + w.z * v2 + w.w * v3;
      }
    }
    for (int t = 0; t < 32; ++t) {
      float p = sps[t];
      cinall[(size_t)(t * 64 + b) * 1024 + 512 + h] = ac[t] * (1.f - p) + ar[t] * p;
    }
  }
}

// ---------------------------------------------------------------------------
// Vocab GEMM (round-8 proven form + nontemporal C stores).  grid 2560 1-D.
// ---------------------------------------------------------------------------
__global__ __launch_bounds__(256) void gemm_vocab(
    const unsigned short* __restrict__ Ab, const unsigned short* __restrict__ Wb,
    const float* __restrict__ bv, float* __restrict__ C)
{
  int lid = blockIdx.x;
  int c = lid & 7, q = lid >> 3, i = q & 15, prow = q >> 4;
  int p = prow * 8 + c;
  if (p >= 157) return;
  int m0 = i * 128, n0 = p * 128;

  __shared__ __align__(16) unsigned short As[128 * 64];
  __shared__ __align__(16) unsigned short Bs[128 * 64];
  int tid = threadIdx.x;
  int wv = tid >> 6, lane = tid & 63;
  int wm = wv >> 1, wn = wv & 1;
  int srow = tid >> 3;
  int scb = (tid & 7) * 16;
  f32x4 acc[4][4];
#pragma unroll
  for (int a = 0; a < 4; ++a)
#pragma unroll
    for (int j = 0; j < 4; ++j) acc[a][j] = (f32x4){0.f, 0.f, 0.f, 0.f};

  for (int k0 = 0; k0 < 512; k0 += 64) {
    __syncthreads();
#pragma unroll
    for (int j = 0; j < 4; ++j) {
      int row = j * 32 + srow;
      uint4 va = *(const uint4*)(Ab + (size_t)(m0 + row) * 512 + k0 + (tid & 7) * 8);
      int brow = n0 + row;
      if (brow > VN - 1) brow = VN - 1;
      uint4 vb = *(const uint4*)(Wb + (size_t)brow * 512 + k0 + (tid & 7) * 8);
      int off = row * 128 + (scb ^ ((row & 7) << 4));
      *(uint4*)((char*)As + off) = va;
      *(uint4*)((char*)Bs + off) = vb;
    }
    __syncthreads();
#pragma unroll
    for (int ks = 0; ks < 2; ++ks) {
      bf16x8 af[4], bf[4];
#pragma unroll
      for (int m = 0; m < 4; ++m) {
        int r = wm * 64 + m * 16 + (lane & 15);
        int cb = (ks * 64 + (lane >> 4) * 16) ^ ((r & 7) << 4);
        af[m] = *(const bf16x8*)((const char*)As + r * 128 + cb);
      }
#pragma unroll
      for (int n = 0; n < 4; ++n) {
        int r = wn * 64 + n * 16 + (lane & 15);
        int cb = (ks * 64 + (lane >> 4) * 16) ^ ((r & 7) << 4);
        bf[n] = *(const bf16x8*)((const char*)Bs + r * 128 + cb);
      }
#pragma unroll
      for (int m = 0; m < 4; ++m)
#pragma unroll
        for (int n = 0; n < 4; ++n)
          acc[m][n] = __builtin_amdgcn_mfma_f32_16x16x32_bf16(af[m], bf[n], acc[m][n], 0, 0, 0);
    }
  }
#pragma unroll
  for (int n = 0; n < 4; ++n) {
    int col = n0 + wn * 64 + n * 16 + (lane & 15);
    if (col >= VN) continue;
    float bvv = bv[col];
#pragma unroll
    for (int m = 0; m < 4; ++m) {
      int rowb = m0 + wm * 64 + m * 16 + (lane >> 4) * 4;
#pragma unroll
      for (int r = 0; r < 4; ++r)
        __builtin_nontemporal_store(acc[m][n][r] + bvv,
                                    &C[(size_t)(rowb + r) * VN + col]);
    }
  }
}

// ---------------------------------------------------------------------------
extern "C" void kernel_launch(void* const* d_in, const int* in_sizes, int n_in,
                              void* d_out, int out_size, void* d_ws, size_t ws_size,
                              hipStream_t stream)
{
  const float* ch   = (const float*)d_in[0];
  const float* ctx  = (const float*)d_in[1];
  const float* ce   = (const float*)d_in[2];
  const float* kb   = (const float*)d_in[3];
  const float* emb  = (const float*)d_in[4];
  const float* Wp   = (const float*)d_in[5];
  const float* bp   = (const float*)d_in[6];
  const float* Wih  = (const float*)d_in[7];
  const float* Whh  = (const float*)d_in[8];
  const float* bih  = (const float*)d_in[9];
  const float* bhh  = (const float*)d_in[10];
  const float* Wgce = (const float*)d_in[11];
  const float* Wgkb = (const float*)d_in[12];
  const float* Wq   = (const float*)d_in[13];
  const float* Wm   = (const float*)d_in[14];
  const float* va   = (const float*)d_in[15];
  const float* ba   = (const float*)d_in[16];
  const float* Wsw  = (const float*)d_in[17];
  const float* bsw  = (const float*)d_in[18];
  const float* Wc   = (const float*)d_in[19];
  const float* bc   = (const float*)d_in[20];
  const float* Wv   = (const float*)d_in[21];
  const float* bv   = (const float*)d_in[22];
  const int* ce_id  = (const int*)d_in[23];
  const int* kb_id  = (const int*)d_in[24];
  const int* kb_row = (const int*)d_in[25];
  const int* target = (const int*)d_in[29];

  float* ws = (float*)d_ws;
  float* rowh   = ws;                        // 1048576 f32
  unsigned short* mempTb = (unsigned short*)(rowh + 1048576);  // 4194304 u16 = 2097152 f32 slots
  float* hall   = rowh + 1048576 + 2097152;  // 1081344 f32
  float* Gx     = hall + 1081344;            // 3145728
  float* qp     = Gx + 3145728;              // 4194304
  float* logits = qp + 4194304;              // 720896
  float* pmlp   = logits + 720896;           // 1048576
  float* wall   = pmlp + 1048576;            // 458752
  float* pswall = wall + 458752;             // 2048
  float* cinall = pswall + 2048;             // 2097152
  unsigned short* callb = (unsigned short*)(cinall + 2097152);   // 524288 f32u
  unsigned short* Wvb   = (unsigned short*)(cinall + 2097152 + 524288); // 5120000 f32u
  unsigned short* WhhH  = (unsigned short*)(cinall + 2097152 + 524288 + 5120000); // 393216 f32u
  unsigned short* WhhL  = (unsigned short*)(cinall + 2097152 + 524288 + 5120000 + 393216); // 393216 f32u
  int* kbo = (int*)(cinall + 2097152 + 524288 + 5120000 + 786432);
  int* kbi = kbo + 64 * 129;
  int* ceo = kbi + 64 * 256;
  int* cei = ceo + 64 * 129;
  int* rwo = cei + 64 * 64;
  int* rwi = rwo + 64 * 33;

  float* vout = (float*)d_out;
  float* pout = vout + (size_t)TN * BN * VN;

  // ---- setup: all independent work in one dispatch, then row_agg ----
  setup_a<<<7632, 256, 0, stream>>>(Whh, WhhH, WhhL, ch, Wp, bp, hall,
                                    emb, target, Wih, bih, Gx,
                                    kb_id, ce_id, kb_row,
                                    kbo, kbi, ceo, cei, rwo, rwi,
                                    Wv, Wvb, ctx, Wm, mempTb);
  row_agg<<<4096, 256, 0, stream>>>(kb, rowh, rwo, rwi);

  // ---- serial GRU chain: 32 plain launches ----
  for (int t = 0; t < TN; ++t)
    step_gru<<<32, 512, 0, stream>>>(
        Gx + (size_t)t * BN * 1536, hall + (size_t)t * BN * HN,
        hall + (size_t)(t + 1) * BN * HN, WhhH, WhhL, bhh);

  // ---- batched phase ----
  gemm_mfma<0, false, true><<<dim3(32, 32), 256, 0, stream>>>(
      hall + BN * HN, nullptr, 0, nullptr, nullptr, nullptr, 0,
      Wgce, Wgkb, Wq, Wc, qp, nullptr, 2048, 2048, 512);
  attn_logits<<<dim3(BN, 27), 256, 0, stream>>>(qp, kb, ce, rowh, mempTb,
                                                va, ba, logits, pmlp);
  attn_reduce_all<<<dim3(BN, TN), 256, 0, stream>>>(
      logits, pmlp, hall, Wsw, bsw, kb_row, kbo, kbi, ceo, cei, rwo, rwi,
      pout, wall, pswall);
  attn_wsum_all<<<dim3(BN, 2, 2), 256, 0, stream>>>(wall, pswall, ctx, ce,
                                                    rowh, cinall);
  gemm_mfma<2, false, false><<<dim3(32, 8), 256, 0, stream>>>(
      cinall, Wc + 512, 1536, bc, nullptr, qp + 1536, 2048,
      nullptr, nullptr, nullptr, nullptr, nullptr, callb, 2048, 512, 1024);
  gemm_vocab<<<2560, 256, 0, stream>>>(callb, Wvb, bv, vout);
}

// Round 22
// 970.157 us; speedup vs baseline: 1.0248x; 1.0248x over previous
//
#include <hip/hip_runtime.h>
#include <math.h>

// Decoder: B=64, H=512, V=20000, Lc=128, Lce=64, Lkb=256, R=32, E=128, T=32
// Round 21 = EXACT resubmission of round 19 (972.9us, best measured).
// Round-20's LOWP mempT regressed (+21us: setup_a is max-over-branches; the
// faster mempT blocks didn't shorten the critical path and perturbed the
// block mix) -> reverted.
// Structure: setup_a (all independent setup, 1 dispatch) -> row_agg ->
// 32x step_gru (K-split MFMA) -> proj GEMM -> attn_logits -> attn_reduce ->
// attn_wsum -> cat GEMM -> vocab GEMM (bf16 MFMA, XCD swizzle, nontemporal).
// Truncation split8 everywhere; cheap tanh; CSR-bucketed gathers.
// No atomics -> deterministic.

#define BN   64
#define HN   512
#define VN   20000
#define LCN  128
#define LCEN 64
#define LKBN 256
#define RN   32
#define EN   128
#define TN   32
#define NEGV -1e9f

typedef __attribute__((ext_vector_type(8))) short bf16x8;
typedef __attribute__((ext_vector_type(4))) float f32x4;

__device__ __forceinline__ float fast_tanh(float x) {
  float e = __expf(2.f * x);
  return 1.f - __fdividef(2.f, 1.f + e);
}
__device__ __forceinline__ float fast_sigm(float x) {
  return __fdividef(1.f, 1.f + __expf(-x));
}

__device__ __forceinline__ unsigned short f2bf(float f) {
  unsigned int u = __float_as_uint(f);
  unsigned int r = (u + 0x7FFFu + ((u >> 16) & 1u)) >> 16;
  return (unsigned short)r;
}
__device__ __forceinline__ float bf2f(unsigned short u) {
  return __uint_as_float((unsigned int)u << 16);
}

// Truncation split: hi = top 16 bits (v - hi exact), lo = round(v - hi).
__device__ __forceinline__ void split8(const float* v, bf16x8& hi, bf16x8& lo) {
#pragma unroll
  for (int i = 0; i < 8; ++i) {
    unsigned int u = __float_as_uint(v[i]);
    unsigned short h = (unsigned short)(u >> 16);
    hi[i] = (short)h;
    lo[i] = (short)f2bf(v[i] - __uint_as_float((unsigned int)h << 16));
  }
}

// ---------------------------------------------------------------------------
// LDS-free split-bf16 MFMA GEMM body (proven pattern, rounds 5-19).
// EPI: 0 plain f32 (+bias); 1 relu f32 (+bias); 2 cat bf16(tanh(x+addm+bias));
//      3 TRS f32 store; 4 TRS bf16 store.
// ---------------------------------------------------------------------------
template <int EPI, bool GATHER, bool PROJ>
__device__ __forceinline__ void gemm_mfma_body(
    int bx, int by,
    const float* __restrict__ A, const float* __restrict__ W, int wstride,
    const float* __restrict__ bias, const int* __restrict__ target,
    const float* __restrict__ addm, int astride,
    const float* __restrict__ Wce, const float* __restrict__ Wkb,
    const float* __restrict__ Wq, const float* __restrict__ Wc,
    float* __restrict__ Cf, unsigned short* __restrict__ Cb,
    int M, int N, int K)
{
  int tid = threadIdx.x & 255, wv = tid >> 6, lane = tid & 63;
  int m0 = bx * 64, n0 = by * 64;
  int wm = (wv >> 1) * 32, wn = (wv & 1) * 32;
  int lr = lane & 15, kg = (lane >> 4) * 8;

  const float* arow[2];
#pragma unroll
  for (int mt = 0; mt < 2; ++mt) {
    int m = m0 + wm + mt * 16 + lr;
    if (GATHER) {
      int tt = m >> 6, bb = m & 63;
      int tok = (tt == 0) ? 2 : target[bb * TN + (tt - 1)];
      arow[mt] = A + (size_t)tok * K + kg;
    } else {
      arow[mt] = A + (size_t)m * K + kg;
    }
  }
  const float* wrow[2];
#pragma unroll
  for (int nt = 0; nt < 2; ++nt) {
    int nr = n0 + wn + nt * 16 + lr;
    if (PROJ) {
      if (nr < 512)       wrow[nt] = Wce + (size_t)nr * 512 + kg;
      else if (nr < 1024) wrow[nt] = Wkb + (size_t)(nr - 512) * 512 + kg;
      else if (nr < 1536) wrow[nt] = Wq + (size_t)(nr - 1024) * 512 + kg;
      else                wrow[nt] = Wc + (size_t)(nr - 1536) * 1536 + kg;
    } else {
      wrow[nt] = W + (size_t)nr * wstride + kg;
    }
  }

  f32x4 acc[2][2];
#pragma unroll
  for (int i = 0; i < 2; ++i)
#pragma unroll
    for (int j = 0; j < 2; ++j) acc[i][j] = (f32x4){0.f, 0.f, 0.f, 0.f};

  for (int ko = 0; ko < K; ko += 32) {
    bf16x8 ah[2], al[2], bh[2], bl[2];
#pragma unroll
    for (int mt = 0; mt < 2; ++mt) {
      float av[8];
      *(float4*)(av + 0) = *(const float4*)(arow[mt] + ko);
      *(float4*)(av + 4) = *(const float4*)(arow[mt] + ko + 4);
      split8(av, ah[mt], al[mt]);
    }
#pragma unroll
    for (int nt = 0; nt < 2; ++nt) {
      float wv8[8];
      *(float4*)(wv8 + 0) = *(const float4*)(wrow[nt] + ko);
      *(float4*)(wv8 + 4) = *(const float4*)(wrow[nt] + ko + 4);
      split8(wv8, bh[nt], bl[nt]);
    }
#pragma unroll
    for (int mt = 0; mt < 2; ++mt)
#pragma unroll
      for (int nt = 0; nt < 2; ++nt) {
        acc[mt][nt] = __builtin_amdgcn_mfma_f32_16x16x32_bf16(ah[mt], bh[nt], acc[mt][nt], 0, 0, 0);
        acc[mt][nt] = __builtin_amdgcn_mfma_f32_16x16x32_bf16(ah[mt], bl[nt], acc[mt][nt], 0, 0, 0);
        acc[mt][nt] = __builtin_amdgcn_mfma_f32_16x16x32_bf16(al[mt], bh[nt], acc[mt][nt], 0, 0, 0);
      }
  }

#pragma unroll
  for (int mt = 0; mt < 2; ++mt)
#pragma unroll
    for (int nt = 0; nt < 2; ++nt) {
      int col = n0 + wn + nt * 16 + lr;
      int rowb = m0 + wm + mt * 16 + (lane >> 4) * 4;
#pragma unroll
      for (int r = 0; r < 4; ++r) {
        int m = rowb + r;
        float v = acc[mt][nt][r];
        if (EPI == 0) {
          if (bias) v += bias[col];
          Cf[(size_t)m * N + col] = v;
        } else if (EPI == 1) {
          if (bias) v += bias[col];
          Cf[(size_t)m * N + col] = fmaxf(v, 0.f);
        } else if (EPI == 2) {
          v += addm[(size_t)m * astride + col] + bias[col];
          Cb[(size_t)m * N + col] = f2bf(fast_tanh(v));
        } else if (EPI == 3) {
          Cf[((size_t)(m >> 7) * N + col) * 128 + (m & 127)] = v;
        } else {
          Cb[((size_t)(m >> 7) * N + col) * 128 + (m & 127)] = f2bf(v);
        }
      }
    }
}

template <int EPI, bool GATHER, bool PROJ>
__global__ __launch_bounds__(256) void gemm_mfma(
    const float* __restrict__ A, const float* __restrict__ W, int wstride,
    const float* __restrict__ bias, const int* __restrict__ target,
    const float* __restrict__ addm, int astride,
    const float* __restrict__ Wce, const float* __restrict__ Wkb,
    const float* __restrict__ Wq, const float* __restrict__ Wc,
    float* __restrict__ Cf, unsigned short* __restrict__ Cb,
    int M, int N, int K)
{
  gemm_mfma_body<EPI, GATHER, PROJ>(blockIdx.x, blockIdx.y, A, W, wstride,
                                    bias, target, addm, astride, Wce, Wkb, Wq,
                                    Wc, Cf, Cb, M, N, K);
}

// ---------------------------------------------------------------------------
// setup_a: ALL independent setup in one dispatch.  grid 7632, 256 thr.
//   [0,768) Whh split | [768,776) h0 | [776,1544) Gx | [1544,1608) CSR |
//   [1608,6608) Wv conv | [6608,7632) mempT (split GEMM, EPI=4 bf16 store)
// ---------------------------------------------------------------------------
__global__ __launch_bounds__(256) void setup_a(
    const float* __restrict__ Whh, unsigned short* __restrict__ WhhH,
    unsigned short* __restrict__ WhhL,
    const float* __restrict__ ch, const float* __restrict__ Wp,
    const float* __restrict__ bp, float* __restrict__ hall,
    const float* __restrict__ emb, const int* __restrict__ target,
    const float* __restrict__ Wih, const float* __restrict__ bih,
    float* __restrict__ Gx,
    const int* __restrict__ kbid, const int* __restrict__ ceid,
    const int* __restrict__ krow,
    int* __restrict__ kbo, int* __restrict__ kbi,
    int* __restrict__ ceo, int* __restrict__ cei,
    int* __restrict__ rwo, int* __restrict__ rwi,
    const float* __restrict__ Wv, unsigned short* __restrict__ Wvb,
    const float* __restrict__ ctx, const float* __restrict__ Wm,
    unsigned short* __restrict__ mempTb)
{
  int bid = blockIdx.x, tid = threadIdx.x;
  if (bid < 768) {
    int i = (bid * 256 + tid) * 4;
    if (i >= 1536 * 512) return;
    float4 v = *(const float4*)(Whh + i);
    float vv[4] = {v.x, v.y, v.z, v.w};
#pragma unroll
    for (int j = 0; j < 4; ++j) {
      unsigned int u = __float_as_uint(vv[j]);
      unsigned short h = (unsigned short)(u >> 16);
      WhhH[i + j] = h;
      WhhL[i + j] = f2bf(vv[j] - __uint_as_float((unsigned int)h << 16));
    }
  } else if (bid < 776) {
    gemm_mfma_body<1, false, false>(0, bid - 768, ch, Wp, 512, bp, nullptr,
                                    nullptr, 0, nullptr, nullptr, nullptr,
                                    nullptr, hall, nullptr, 64, 512, 512);
  } else if (bid < 1544) {
    int i = bid - 776;
    gemm_mfma_body<0, true, false>(i % 32, i / 32, emb, Wih, 512, bih, target,
                                   nullptr, 0, nullptr, nullptr, nullptr,
                                   nullptr, Gx, nullptr, 2048, 1536, 512);
  } else if (bid < 1608) {
    int b = bid - 1544;
    __shared__ int sid[256], srw[256], scid[64];
    __shared__ int cnt[128], off[129];
    sid[tid] = kbid[b * LKBN + tid];
    srw[tid] = krow[b * LKBN + tid];
    if (tid < 64) scid[tid] = ceid[b * LCEN + tid];
    __syncthreads();
    if (tid < 128) {
      int c = 0;
      for (int k = 0; k < 256; ++k) c += (sid[k] == tid);
      cnt[tid] = c;
    }
    __syncthreads();
    if (tid == 0) {
      int o = 0;
      for (int e = 0; e < 128; ++e) { off[e] = o; o += cnt[e]; }
      off[128] = o;
    }
    __syncthreads();
    if (tid < 128) {
      int w = off[tid];
      for (int k = 0; k < 256; ++k) if (sid[k] == tid) kbi[b * 256 + (w++)] = k;
      kbo[b * 129 + tid] = off[tid];
      if (tid == 0) kbo[b * 129 + 128] = off[128];
    }
    __syncthreads();
    if (tid < 128) {
      int c = 0;
      for (int k = 0; k < 64; ++k) c += (scid[k] == tid);
      cnt[tid] = c;
    }
    __syncthreads();
    if (tid == 0) {
      int o = 0;
      for (int e = 0; e < 128; ++e) { off[e] = o; o += cnt[e]; }
      off[128] = o;
    }
    __syncthreads();
    if (tid < 128) {
      int w = off[tid];
      for (int k = 0; k < 64; ++k) if (scid[k] == tid) cei[b * 64 + (w++)] = k;
      ceo[b * 129 + tid] = off[tid];
      if (tid == 0) ceo[b * 129 + 128] = off[128];
    }
    __syncthreads();
    if (tid < 32) {
      int c = 0;
      for (int k = 0; k < 256; ++k) c += (srw[k] == tid);
      cnt[tid] = c;
    }
    __syncthreads();
    if (tid == 0) {
      int o = 0;
      for (int r = 0; r < 32; ++r) { off[r] = o; o += cnt[r]; }
      off[32] = o;
    }
    __syncthreads();
    if (tid < 32) {
      int w = off[tid];
      for (int k = 0; k < 256; ++k) if (srw[k] == tid) rwi[b * 256 + (w++)] = k;
      rwo[b * 33 + tid] = off[tid];
      if (tid == 0) rwo[b * 33 + 32] = off[32];
    }
  } else if (bid < 6608) {
    size_t i = ((size_t)(bid - 1608) * 256 + tid) * 8;
    if (i >= (size_t)VN * HN) return;
    float4 v0 = *(const float4*)(Wv + i);
    float4 v1 = *(const float4*)(Wv + i + 4);
    unsigned short o[8];
    o[0] = f2bf(v0.x); o[1] = f2bf(v0.y); o[2] = f2bf(v0.z); o[3] = f2bf(v0.w);
    o[4] = f2bf(v1.x); o[5] = f2bf(v1.y); o[6] = f2bf(v1.z); o[7] = f2bf(v1.w);
    *(uint4*)(Wvb + i) = *(const uint4*)o;
  } else {
    int i = bid - 6608;
    gemm_mfma_body<4, false, false>(i % 128, i / 128, ctx, Wm, 512, nullptr,
                                    nullptr, nullptr, 0, nullptr, nullptr,
                                    nullptr, nullptr, nullptr, mempTb,
                                    8192, 512, 512);
  }
}

// ---------------------------------------------------------------------------
// row_agg: thread-per-output via CSR (round-16 proven).  grid 4096, 256 thr.
// ---------------------------------------------------------------------------
__global__ __launch_bounds__(256) void row_agg(
    const float* __restrict__ kb, float* __restrict__ rowh,
    const int* __restrict__ rwo, const int* __restrict__ rwi)
{
  int s = blockIdx.x, tid = threadIdx.x;
  int b = s >> 6;
  int rem = s & 63;
  int r = rem >> 1, half = rem & 1;
  int h = half * 256 + tid;
  int p0 = rwo[b * 33 + r], p1 = rwo[b * 33 + r + 1];
  const float* kbb = kb + (size_t)b * LKBN * HN + h;
  float sum = 0.f;
  for (int p = p0; p < p1; ++p)
    sum += kbb[(size_t)rwi[b * 256 + p] * HN];
  float cnt = (float)(p1 - p0);
  rowh[((size_t)b * RN + r) * HN + h] = sum / fmaxf(cnt, 1.f);
}

// ---------------------------------------------------------------------------
// Serial GRU step, 512 thr / 8 waves, 2-way K-split (round-10 proven).
// ---------------------------------------------------------------------------
__global__ __launch_bounds__(512) void step_gru(
    const float* __restrict__ Gx, const float* __restrict__ hprev,
    float* __restrict__ hnew, const unsigned short* __restrict__ WhhH,
    const unsigned short* __restrict__ WhhL, const float* __restrict__ bhh)
{
  __shared__ float red[3072];
  int tid = threadIdx.x;
  int w = tid >> 6, lane = tid & 63;
  int kh = w >> 2, mg = w & 3;
  int j0 = blockIdx.x * 16;
  int m0 = mg * 16;
  int lr = lane & 15, kg = (lane >> 4) * 8;
  int kbase = kh * 256;

  f32x4 acc[3];
#pragma unroll
  for (int g = 0; g < 3; ++g) acc[g] = (f32x4){0.f, 0.f, 0.f, 0.f};
  const float* ap = hprev + (size_t)(m0 + lr) * 512 + kbase + kg;
  const unsigned short* bhp = WhhH + (size_t)(j0 + lr) * 512 + kbase + kg;
  const unsigned short* blp = WhhL + (size_t)(j0 + lr) * 512 + kbase + kg;
#pragma unroll
  for (int ks = 0; ks < 8; ++ks) {
    int ko = ks * 32;
    float av[8];
    *(float4*)(av + 0) = *(const float4*)(ap + ko);
    *(float4*)(av + 4) = *(const float4*)(ap + ko + 4);
    bf16x8 ah, al;
    split8(av, ah, al);
#pragma unroll
    for (int g = 0; g < 3; ++g) {
      bf16x8 bh = *(const bf16x8*)(bhp + (size_t)g * 512 * 512 + ko);
      bf16x8 bl = *(const bf16x8*)(blp + (size_t)g * 512 * 512 + ko);
      acc[g] = __builtin_amdgcn_mfma_f32_16x16x32_bf16(ah, bh, acc[g], 0, 0, 0);
      acc[g] = __builtin_amdgcn_mfma_f32_16x16x32_bf16(ah, bl, acc[g], 0, 0, 0);
      acc[g] = __builtin_amdgcn_mfma_f32_16x16x32_bf16(al, bh, acc[g], 0, 0, 0);
    }
  }

  if (kh == 1) {
#pragma unroll
    for (int g = 0; g < 3; ++g)
#pragma unroll
      for (int r = 0; r < 4; ++r)
        red[(mg * 3 + g) * 256 + lane * 4 + r] = acc[g][r];
  }
  __syncthreads();
  if (kh == 0) {
#pragma unroll
    for (int g = 0; g < 3; ++g)
#pragma unroll
      for (int r = 0; r < 4; ++r)
        acc[g][r] += red[(mg * 3 + g) * 256 + lane * 4 + r];
    int j = j0 + lr;
#pragma unroll
    for (int r = 0; r < 4; ++r) {
      int b = m0 + (lane >> 4) * 4 + r;
      const float* gx = Gx + (size_t)b * 1536;
      float rr = fast_sigm(gx[j] + acc[0][r] + bhh[j]);
      float z  = fast_sigm(gx[512 + j] + acc[1][r] + bhh[512 + j]);
      float n  = fast_tanh(gx[1024 + j] + rr * (acc[2][r] + bhh[1024 + j]));
      float hp = hprev[(size_t)b * 512 + j];
      hnew[(size_t)b * 512 + j] = (1.f - z) * n + z * hp;
    }
  }
}

// ---------------------------------------------------------------------------
// Fused attention logits.  grid (64, 27), 256 thr.  mempT read as bf16.
// ---------------------------------------------------------------------------
__global__ __launch_bounds__(256) void attn_logits(
    const float* __restrict__ qp, const float* __restrict__ kb,
    const float* __restrict__ ce, const float* __restrict__ rowh,
    const unsigned short* __restrict__ mempTb, const float* __restrict__ va,
    const float* __restrict__ ba, float* __restrict__ logits,
    float* __restrict__ pmlp)
{
  int b = blockIdx.x, nt = blockIdx.y;
  int tid = threadIdx.x;
  if (nt < 11) {
    int wv = tid >> 6, lane = tid & 63;
    int lr = lane & 15, kg = (lane >> 4) * 8;
    const float* keys; int keybase, qoff, gkbase;
    if (nt < 8)       { keys = kb + (size_t)b * 256 * 512;  keybase = nt * 32;       qoff = 512; gkbase = keybase; }
    else if (nt < 10) { keys = ce + (size_t)b * 64 * 512;   keybase = (nt - 8) * 32; qoff = 0;   gkbase = 256 + keybase; }
    else              { keys = rowh + (size_t)b * 32 * 512; keybase = 0;             qoff = 512; gkbase = 320; }
    int mhalf = wv >> 1, nhalf = wv & 1;
    const float* ap = qp + (size_t)((mhalf * 16 + lr) * 64 + b) * 2048 + qoff + kg;
    const float* bp = keys + (size_t)(keybase + nhalf * 16 + lr) * 512 + kg;
    f32x4 acc = {0.f, 0.f, 0.f, 0.f};
#pragma unroll 4
    for (int ks = 0; ks < 16; ++ks) {
      int ko = ks * 32;
      float av[8], bv[8];
      *(float4*)(av + 0) = *(const float4*)(ap + ko);
      *(float4*)(av + 4) = *(const float4*)(ap + ko + 4);
      *(float4*)(bv + 0) = *(const float4*)(bp + ko);
      *(float4*)(bv + 4) = *(const float4*)(bp + ko + 4);
      bf16x8 ah, al, bh, bl;
      split8(av, ah, al);
      split8(bv, bh, bl);
      acc = __builtin_amdgcn_mfma_f32_16x16x32_bf16(ah, bh, acc, 0, 0, 0);
      acc = __builtin_amdgcn_mfma_f32_16x16x32_bf16(ah, bl, acc, 0, 0, 0);
      acc = __builtin_amdgcn_mfma_f32_16x16x32_bf16(al, bh, acc, 0, 0, 0);
    }
    int gk = gkbase + nhalf * 16 + lr;
#pragma unroll
    for (int r = 0; r < 4; ++r) {
      int t = mhalf * 16 + (lane >> 4) * 4 + r;
      logits[((size_t)b * 32 + t) * 352 + gk] = acc[r];
    }
  } else {
    int zz = nt - 11;
    int ch = zz & 3, tg = zz >> 2;
    int h0 = ch << 7;
    __shared__ float sq[8][128];
    __shared__ float sv[128];
    for (int idx = tid; idx < 1024; idx += 256) {
      int tl = idx >> 7, i = idx & 127;
      int t = tg * 8 + tl;
      sq[tl][i] = qp[(size_t)(t * 64 + b) * 2048 + 1024 + h0 + i] + ba[h0 + i];
    }
    if (tid < 128) sv[tid] = va[h0 + tid];
    __syncthreads();
    int k = tid & 127, th = tid >> 7;
    const unsigned short* mp = mempTb + ((size_t)b * 512 + h0) * 128 + k;
    float acc[4] = {};
    for (int h = 0; h < 128; ++h) {
      float mv = bf2f(mp[h * 128]);
      float vah = sv[h];
#pragma unroll
      for (int i = 0; i < 4; ++i)
        acc[i] += vah * fast_tanh(sq[th * 4 + i][h] + mv);
    }
#pragma unroll
    for (int i = 0; i < 4; ++i) {
      int t = tg * 8 + th * 4 + i;
      pmlp[(((size_t)b * 4 + ch) * 32 + t) * 128 + k] = acc[i];
    }
  }
}

// ---------------------------------------------------------------------------
// Reduce: softmaxes + p_entity + weights out (CSR-bucketed, __expf).
// grid (64, 32), 256 thr.
// ---------------------------------------------------------------------------
__global__ __launch_bounds__(256) void attn_reduce_all(
    const float* __restrict__ logits, const float* __restrict__ pmlp,
    const float* __restrict__ hall, const float* __restrict__ Wsw,
    const float* __restrict__ bsw, const int* __restrict__ krow,
    const int* __restrict__ kbo, const int* __restrict__ kbi,
    const int* __restrict__ ceo, const int* __restrict__ cei,
    const int* __restrict__ rwo, const int* __restrict__ rwi,
    float* __restrict__ pout, float* __restrict__ wall,
    float* __restrict__ pswall)
{
  int b = blockIdx.x, t = blockIdx.y, tid = threadIdx.x;
  int wv = tid >> 6, lane = tid & 63;
  __shared__ float s_l[480];
  __shared__ float s_kbp[256];
  __shared__ float s_wce[64], s_wrow[32], s_wc[128];
  __shared__ float s_rmax[32], s_rsum[32];
  __shared__ int s_krow[256];
  __shared__ float s_red[4];
  __shared__ float s_psw;

  const float* lg = logits + ((size_t)b * 32 + t) * 352;
  for (int k = tid; k < 352; k += 256) s_l[k] = lg[k];
  if (tid < 128) {
    const float* pm = pmlp + ((size_t)b * 4 * 32 + t) * 128 + tid;
    s_l[352 + tid] = pm[0] + pm[4096] + pm[8192] + pm[12288];
  }
  {
    const float* hp = hall + ((size_t)(t + 1) * 64 + b) * 512;
    float ps = hp[tid] * Wsw[tid] + hp[tid + 256] * Wsw[tid + 256];
    for (int o = 32; o; o >>= 1) ps += __shfl_down(ps, o);
    if (lane == 0) s_red[wv] = ps;
  }
  s_krow[tid] = krow[b * LKBN + tid];
  __syncthreads();
  if (tid == 0) s_psw = fast_sigm(s_red[0] + s_red[1] + s_red[2] + s_red[3] + bsw[0]);

  if (wv == 0) {
    {
      float v = s_l[256 + lane];
      float m = v;
      for (int o = 32; o; o >>= 1) m = fmaxf(m, __shfl_xor(m, o));
      float e = __expf(v - m), s = e;
      for (int o = 32; o; o >>= 1) s += __shfl_xor(s, o);
      s_wce[lane] = e / s;
    }
    {
      float v;
      if (lane < 32) {
        bool empty = rwo[b * 33 + lane + 1] == rwo[b * 33 + lane];
        v = empty ? NEGV : s_l[320 + lane];
      } else v = -INFINITY;
      float m = v;
      for (int o = 32; o; o >>= 1) m = fmaxf(m, __shfl_xor(m, o));
      float e = (lane < 32) ? __expf(v - m) : 0.f, s = e;
      for (int o = 32; o; o >>= 1) s += __shfl_xor(s, o);
      if (lane < 32) s_wrow[lane] = e / s;
    }
  } else if (wv == 1) {
    float v0 = s_l[352 + lane], v1 = s_l[352 + 64 + lane];
    float m = fmaxf(v0, v1);
    for (int o = 32; o; o >>= 1) m = fmaxf(m, __shfl_xor(m, o));
    float e0 = __expf(v0 - m), e1 = __expf(v1 - m);
    float s = e0 + e1;
    for (int o = 32; o; o >>= 1) s += __shfl_xor(s, o);
    s_wc[lane] = e0 / s;
    s_wc[lane + 64] = e1 / s;
  } else {
    int r = (tid - 128) >> 2, i = (tid - 128) & 3;
    int p0 = rwo[b * 33 + r], p1 = rwo[b * 33 + r + 1];
    float m = -INFINITY;
    for (int p = p0 + i; p < p1; p += 4) m = fmaxf(m, s_l[rwi[b * 256 + p]]);
    for (int o = 2; o; o >>= 1) m = fmaxf(m, __shfl_xor(m, o));
    float s = 0.f;
    for (int p = p0 + i; p < p1; p += 4) s += __expf(s_l[rwi[b * 256 + p]] - m);
    for (int o = 2; o; o >>= 1) s += __shfl_xor(s, o);
    if (i == 0) { s_rmax[r] = m; s_rsum[r] = s; }
  }
  __syncthreads();
  {
    int r = s_krow[tid];
    s_kbp[tid] = __expf(s_l[tid] - s_rmax[r]) / s_rsum[r] * s_wrow[r];
  }
  __syncthreads();
  if (tid < EN) {
    float a = 0.f;
    for (int p = ceo[b * 129 + tid]; p < ceo[b * 129 + tid + 1]; ++p)
      a += s_wce[cei[b * 64 + p]];
    float pk = 0.f;
    for (int p = kbo[b * 129 + tid]; p < kbo[b * 129 + tid + 1]; ++p)
      pk += s_kbp[kbi[b * 256 + p]];
    float psw = s_psw;
    pout[((size_t)t * BN + b) * EN + tid] = (1.f - psw) * a + psw * pk;
  }
  float* wb = wall + (size_t)(b * 32 + t) * 224;
  if (tid < 64) wb[tid] = s_wce[tid];
  else if (tid < 96) wb[tid] = s_wrow[tid - 64];
  else if (tid < 224) wb[tid] = s_wc[tid - 96];
  if (tid == 0) pswall[b * 32 + t] = s_psw;
}

// ---------------------------------------------------------------------------
// Batched weighted sums.  grid (64, 2, 2), 256 thr.  kind z: 0=ctx, 1=entity.
// ---------------------------------------------------------------------------
__global__ __launch_bounds__(256) void attn_wsum_all(
    const float* __restrict__ wall, const float* __restrict__ pswall,
    const float* __restrict__ ctx, const float* __restrict__ ce,
    const float* __restrict__ rowh, float* __restrict__ cinall)
{
  int b = blockIdx.x, half = blockIdx.y, kind = blockIdx.z;
  int tid = threadIdx.x;
  int h = half * 256 + tid;
  if (kind == 0) {
    __shared__ float wc[32][128];
    for (int idx = tid; idx < 4096; idx += 256)
      wc[idx >> 7][idx & 127] = wall[(size_t)(b * 32 + (idx >> 7)) * 224 + 96 + (idx & 127)];
    __syncthreads();
    const float* xb = ctx + (size_t)b * 128 * 512 + h;
    float acc[32] = {};
    for (int k = 0; k < 128; k += 4) {
      float v0 = xb[(k + 0) * 512], v1 = xb[(k + 1) * 512];
      float v2 = xb[(k + 2) * 512], v3 = xb[(k + 3) * 512];
#pragma unroll
      for (int t = 0; t < 32; ++t) {
        float4 w = *(const float4*)&wc[t][k];
        acc[t] += w.x * v0 + w.y * v1 + w.z * v2 + w.w * v3;
      }
    }
    for (int t = 0; t < 32; ++t)
      cinall[(size_t)(t * 64 + b) * 1024 + h] = acc[t];
  } else {
    __shared__ float wce[32][64];
    __shared__ float wr[32][32];
    __shared__ float sps[32];
    for (int idx = tid; idx < 2048; idx += 256)
      wce[idx >> 6][idx & 63] = wall[(size_t)(b * 32 + (idx >> 6)) * 224 + (idx & 63)];
    for (int idx = tid; idx < 1024; idx += 256)
      wr[idx >> 5][idx & 31] = wall[(size_t)(b * 32 + (idx >> 5)) * 224 + 64 + (idx & 31)];
    if (tid < 32) sps[tid] = pswall[b * 32 + tid];
    __syncthreads();
    const float* cb = ce + (size_t)b * 64 * 512 + h;
    float ac[32] = {};
    for (int k = 0; k < 64; k += 4) {
      float v0 = cb[(k + 0) * 512], v1 = cb[(k + 1) * 512];
      float v2 = cb[(k + 2) * 512], v3 = cb[(k + 3) * 512];
#pragma unroll
      for (int t = 0; t < 32; ++t) {
        float4 w = *(const float4*)&wce[t][k];
        ac[t] += w.x * v0 + w.y * v1 + w.z * v2 + w.w * v3;
      }
    }
    const float* rb = rowh + (size_t)b * 32 * 512 + h;
    float ar[32] = {};
    for (int k = 0; k < 32; k += 4) {
      float v0 = rb[(k + 0) * 512], v1 = rb[(k + 1) * 512];
      float v2 = rb[(k + 2) * 512], v3 = rb[(k + 3) * 512];
#pragma unroll
      for (int t = 0; t < 32; ++t) {
        float4 w = *(const float4*)&wr[t][k];
        ar[t] += w.x * v0 + w.y * v1 + w.z * v2 + w.w * v3;
      }
    }
    for (int t = 0; t < 32; ++t) {
      float p = sps[t];
      cinall[(size_t)(t * 64 + b) * 1024 + 512 + h] = ac[t] * (1.f - p) + ar[t] * p;
    }
  }
}

// ---------------------------------------------------------------------------
// Vocab GEMM (round-8 proven form + nontemporal C stores).  grid 2560 1-D.
// ---------------------------------------------------------------------------
__global__ __launch_bounds__(256) void gemm_vocab(
    const unsigned short* __restrict__ Ab, const unsigned short* __restrict__ Wb,
    const float* __restrict__ bv, float* __restrict__ C)
{
  int lid = blockIdx.x;
  int c = lid & 7, q = lid >> 3, i = q & 15, prow = q >> 4;
  int p = prow * 8 + c;
  if (p >= 157) return;
  int m0 = i * 128, n0 = p * 128;

  __shared__ __align__(16) unsigned short As[128 * 64];
  __shared__ __align__(16) unsigned short Bs[128 * 64];
  int tid = threadIdx.x;
  int wv = tid >> 6, lane = tid & 63;
  int wm = wv >> 1, wn = wv & 1;
  int srow = tid >> 3;
  int scb = (tid & 7) * 16;
  f32x4 acc[4][4];
#pragma unroll
  for (int a = 0; a < 4; ++a)
#pragma unroll
    for (int j = 0; j < 4; ++j) acc[a][j] = (f32x4){0.f, 0.f, 0.f, 0.f};

  for (int k0 = 0; k0 < 512; k0 += 64) {
    __syncthreads();
#pragma unroll
    for (int j = 0; j < 4; ++j) {
      int row = j * 32 + srow;
      uint4 va = *(const uint4*)(Ab + (size_t)(m0 + row) * 512 + k0 + (tid & 7) * 8);
      int brow = n0 + row;
      if (brow > VN - 1) brow = VN - 1;
      uint4 vb = *(const uint4*)(Wb + (size_t)brow * 512 + k0 + (tid & 7) * 8);
      int off = row * 128 + (scb ^ ((row & 7) << 4));
      *(uint4*)((char*)As + off) = va;
      *(uint4*)((char*)Bs + off) = vb;
    }
    __syncthreads();
#pragma unroll
    for (int ks = 0; ks < 2; ++ks) {
      bf16x8 af[4], bf[4];
#pragma unroll
      for (int m = 0; m < 4; ++m) {
        int r = wm * 64 + m * 16 + (lane & 15);
        int cb = (ks * 64 + (lane >> 4) * 16) ^ ((r & 7) << 4);
        af[m] = *(const bf16x8*)((const char*)As + r * 128 + cb);
      }
#pragma unroll
      for (int n = 0; n < 4; ++n) {
        int r = wn * 64 + n * 16 + (lane & 15);
        int cb = (ks * 64 + (lane >> 4) * 16) ^ ((r & 7) << 4);
        bf[n] = *(const bf16x8*)((const char*)Bs + r * 128 + cb);
      }
#pragma unroll
      for (int m = 0; m < 4; ++m)
#pragma unroll
        for (int n = 0; n < 4; ++n)
          acc[m][n] = __builtin_amdgcn_mfma_f32_16x16x32_bf16(af[m], bf[n], acc[m][n], 0, 0, 0);
    }
  }
#pragma unroll
  for (int n = 0; n < 4; ++n) {
    int col = n0 + wn * 64 + n * 16 + (lane & 15);
    if (col >= VN) continue;
    float bvv = bv[col];
#pragma unroll
    for (int m = 0; m < 4; ++m) {
      int rowb = m0 + wm * 64 + m * 16 + (lane >> 4) * 4;
#pragma unroll
      for (int r = 0; r < 4; ++r)
        __builtin_nontemporal_store(acc[m][n][r] + bvv,
                                    &C[(size_t)(rowb + r) * VN + col]);
    }
  }
}

// ---------------------------------------------------------------------------
extern "C" void kernel_launch(void* const* d_in, const int* in_sizes, int n_in,
                              void* d_out, int out_size, void* d_ws, size_t ws_size,
                              hipStream_t stream)
{
  const float* ch   = (const float*)d_in[0];
  const float* ctx  = (const float*)d_in[1];
  const float* ce   = (const float*)d_in[2];
  const float* kb   = (const float*)d_in[3];
  const float* emb  = (const float*)d_in[4];
  const float* Wp   = (const float*)d_in[5];
  const float* bp   = (const float*)d_in[6];
  const float* Wih  = (const float*)d_in[7];
  const float* Whh  = (const float*)d_in[8];
  const float* bih  = (const float*)d_in[9];
  const float* bhh  = (const float*)d_in[10];
  const float* Wgce = (const float*)d_in[11];
  const float* Wgkb = (const float*)d_in[12];
  const float* Wq   = (const float*)d_in[13];
  const float* Wm   = (const float*)d_in[14];
  const float* va   = (const float*)d_in[15];
  const float* ba   = (const float*)d_in[16];
  const float* Wsw  = (const float*)d_in[17];
  const float* bsw  = (const float*)d_in[18];
  const float* Wc   = (const float*)d_in[19];
  const float* bc   = (const float*)d_in[20];
  const float* Wv   = (const float*)d_in[21];
  const float* bv   = (const float*)d_in[22];
  const int* ce_id  = (const int*)d_in[23];
  const int* kb_id  = (const int*)d_in[24];
  const int* kb_row = (const int*)d_in[25];
  const int* target = (const int*)d_in[29];

  float* ws = (float*)d_ws;
  float* rowh   = ws;                        // 1048576 f32
  unsigned short* mempTb = (unsigned short*)(rowh + 1048576);  // 4194304 u16 = 2097152 f32 slots
  float* hall   = rowh + 1048576 + 2097152;  // 1081344 f32
  float* Gx     = hall + 1081344;            // 3145728
  float* qp     = Gx + 3145728;              // 4194304
  float* logits = qp + 4194304;              // 720896
  float* pmlp   = logits + 720896;           // 1048576
  float* wall   = pmlp + 1048576;            // 458752
  float* pswall = wall + 458752;             // 2048
  float* cinall = pswall + 2048;             // 2097152
  unsigned short* callb = (unsigned short*)(cinall + 2097152);   // 524288 f32u
  unsigned short* Wvb   = (unsigned short*)(cinall + 2097152 + 524288); // 5120000 f32u
  unsigned short* WhhH  = (unsigned short*)(cinall + 2097152 + 524288 + 5120000); // 393216 f32u
  unsigned short* WhhL  = (unsigned short*)(cinall + 2097152 + 524288 + 5120000 + 393216); // 393216 f32u
  int* kbo = (int*)(cinall + 2097152 + 524288 + 5120000 + 786432);
  int* kbi = kbo + 64 * 129;
  int* ceo = kbi + 64 * 256;
  int* cei = ceo + 64 * 129;
  int* rwo = cei + 64 * 64;
  int* rwi = rwo + 64 * 33;

  float* vout = (float*)d_out;
  float* pout = vout + (size_t)TN * BN * VN;

  // ---- setup: all independent work in one dispatch, then row_agg ----
  setup_a<<<7632, 256, 0, stream>>>(Whh, WhhH, WhhL, ch, Wp, bp, hall,
                                    emb, target, Wih, bih, Gx,
                                    kb_id, ce_id, kb_row,
                                    kbo, kbi, ceo, cei, rwo, rwi,
                                    Wv, Wvb, ctx, Wm, mempTb);
  row_agg<<<4096, 256, 0, stream>>>(kb, rowh, rwo, rwi);

  // ---- serial GRU chain: 32 plain launches ----
  for (int t = 0; t < TN; ++t)
    step_gru<<<32, 512, 0, stream>>>(
        Gx + (size_t)t * BN * 1536, hall + (size_t)t * BN * HN,
        hall + (size_t)(t + 1) * BN * HN, WhhH, WhhL, bhh);

  // ---- batched phase ----
  gemm_mfma<0, false, true><<<dim3(32, 32), 256, 0, stream>>>(
      hall + BN * HN, nullptr, 0, nullptr, nullptr, nullptr, 0,
      Wgce, Wgkb, Wq, Wc, qp, nullptr, 2048, 2048, 512);
  attn_logits<<<dim3(BN, 27), 256, 0, stream>>>(qp, kb, ce, rowh, mempTb,
                                                va, ba, logits, pmlp);
  attn_reduce_all<<<dim3(BN, TN), 256, 0, stream>>>(
      logits, pmlp, hall, Wsw, bsw, kb_row, kbo, kbi, ceo, cei, rwo, rwi,
      pout, wall, pswall);
  attn_wsum_all<<<dim3(BN, 2, 2), 256, 0, stream>>>(wall, pswall, ctx, ce,
                                                    rowh, cinall);
  gemm_mfma<2, false, false><<<dim3(32, 8), 256, 0, stream>>>(
      cinall, Wc + 512, 1536, bc, nullptr, qp + 1536, 2048,
      nullptr, nullptr, nullptr, nullptr, nullptr, callb, 2048, 512, 1024);
  gemm_vocab<<<2560, 256, 0, stream>>>(callb, Wvb, bv, vout);
}